// Round 1
// baseline (875.923 us; speedup 1.0000x reference)
//
#include <hip/hip_runtime.h>
#include <hip/hip_bf16.h>
#include <stdint.h>

#define NH 16
#define NKV 8
#define HD 128
#define BB 4
#define SS 1024
#define CTXL 2048
#define LT 3072
#define HID 2048
#define QKVN 4096
#define MROWS 4096

typedef __hip_bfloat16 bf16;
using f32x4 = __attribute__((ext_vector_type(4))) float;
using s16x8 = __attribute__((ext_vector_type(8))) short;

#define MFMA(a, b, c) __builtin_amdgcn_mfma_f32_16x16x32_bf16((a), (b), (c), 0, 0, 0)

__device__ __forceinline__ void gload_lds16(const void* g, void* l) {
  __builtin_amdgcn_global_load_lds((const __attribute__((address_space(1))) void*)g,
                                   (__attribute__((address_space(3))) void*)l, 16, 0, 0);
}

__device__ __forceinline__ void store_bf8(bf16* dst, const float* f) {
  bf16 tmp[8];
#pragma unroll
  for (int j = 0; j < 8; ++j) tmp[j] = __float2bfloat16(f[j]);
  __builtin_memcpy((void*)dst, (const void*)tmp, 16);
}

// ---------------- prep kernels ----------------

__global__ void cvt_bf16(const float* __restrict__ in, bf16* __restrict__ out) {
  size_t tid = (size_t)blockIdx.x * 256 + threadIdx.x;  // one thread per 8 elems
  const float4* p = (const float4*)(in + tid * 8);
  float4 a = p[0], b = p[1];
  float f[8] = {a.x, a.y, a.z, a.w, b.x, b.y, b.z, b.w};
  store_bf8(out + tid * 8, f);
}

// out[c][r] = (bf16) in[r][c]
__global__ void transpose_cvt(const float* __restrict__ in, bf16* __restrict__ out,
                              int R, int C) {
  __shared__ float tile[32][33];
  int c0 = blockIdx.x * 32, r0 = blockIdx.y * 32;
  int tx = threadIdx.x & 31, ty = threadIdx.x >> 5;
#pragma unroll
  for (int i = 0; i < 32; i += 8)
    tile[ty + i][tx] = in[(size_t)(r0 + ty + i) * C + c0 + tx];
  __syncthreads();
#pragma unroll
  for (int i = 0; i < 32; i += 8)
    out[(size_t)(c0 + ty + i) * R + r0 + tx] = __float2bfloat16(tile[tx][ty + i]);
}

// ctx_k [b][l][h][d] f32 -> K_full [b][h][l][d] bf16 (l < CTXL)
__global__ void ctxk_copy(const float* __restrict__ ck, bf16* __restrict__ Kf) {
  int tid = blockIdx.x * 256 + threadIdx.x;
  int d8 = tid & 15, l = (tid >> 4) & 2047, h = (tid >> 15) & 7, b = tid >> 18;
  const float* s = ck + (((size_t)b * CTXL + l) * NKV + h) * HD + d8 * 8;
  const float4* p = (const float4*)s;
  float4 a = p[0], bb = p[1];
  float f[8] = {a.x, a.y, a.z, a.w, bb.x, bb.y, bb.z, bb.w};
  store_bf8(Kf + (((size_t)(b * NKV + h)) * LT + l) * HD + d8 * 8, f);
}

// ctx_v [b][l][h][d] f32 -> V_T [b][h][d][l] bf16 (l < CTXL)
__global__ void ctxv_transpose(const float* __restrict__ cv, bf16* __restrict__ Vt) {
  __shared__ float tile[32][33];
  int l0 = blockIdx.x * 32, d0 = blockIdx.y * 32;
  int b = blockIdx.z >> 3, h = blockIdx.z & 7;
  int tx = threadIdx.x & 31, ty = threadIdx.x >> 5;
#pragma unroll
  for (int i = 0; i < 32; i += 8)
    tile[ty + i][tx] = cv[(((size_t)b * CTXL + l0 + ty + i) * NKV + h) * HD + d0 + tx];
  __syncthreads();
#pragma unroll
  for (int i = 0; i < 32; i += 8)
    Vt[(((size_t)(b * NKV + h)) * HD + d0 + ty + i) * LT + l0 + tx] =
        __float2bfloat16(tile[tx][ty + i]);
}

// qkv v-slice -> V_T tail (l = CTXL + s)
__global__ void vt_from_qkv(const bf16* __restrict__ qkv, bf16* __restrict__ Vt) {
  __shared__ float tile[32][33];
  int s0 = blockIdx.x * 32, d0 = blockIdx.y * 32;
  int b = blockIdx.z >> 3, h = blockIdx.z & 7;
  int tx = threadIdx.x & 31, ty = threadIdx.x >> 5;
#pragma unroll
  for (int i = 0; i < 32; i += 8)
    tile[ty + i][tx] = __bfloat162float(
        qkv[((size_t)b * SS + s0 + ty + i) * QKVN + 3072 + h * HD + d0 + tx]);
  __syncthreads();
#pragma unroll
  for (int i = 0; i < 32; i += 8)
    Vt[(((size_t)(b * NKV + h)) * HD + d0 + ty + i) * LT + CTXL + s0 + tx] =
        __float2bfloat16(tile[tx][ty + i]);
}

__global__ void rope_table(const int* __restrict__ pid, float* __restrict__ cosT,
                           float* __restrict__ sinT) {
  int tid = blockIdx.x * 256 + threadIdx.x;  // S*64
  int j = tid & 63, s = tid >> 6;
  int sec = (j < 8) ? 0 : (j < 16) ? 1 : (j < 40) ? 2 : 3;
  float pos = (float)pid[sec * SS + s];
  float inv = __expf(-(float)j * 0.14391156831212787f);  // ln(10000)/64
  float a = pos * inv;
  cosT[tid] = cosf(a);
  sinT[tid] = sinf(a);
}

__global__ void rope_q(const bf16* __restrict__ qkv, const float* __restrict__ cosT,
                       const float* __restrict__ sinT, bf16* __restrict__ Q) {
  int tid = blockIdx.x * 256 + threadIdx.x;
  int j = tid & 63, h = (tid >> 6) & 15, s = (tid >> 10) & 1023, b = tid >> 20;
  const bf16* src = qkv + ((size_t)b * SS + s) * QKVN + h * HD;
  float x1 = __bfloat162float(src[j]), x2 = __bfloat162float(src[j + 64]);
  float c = cosT[s * 64 + j], sn = sinT[s * 64 + j];
  bf16* dst = Q + (((size_t)(b * NH + h)) * SS + s) * HD;
  dst[j] = __float2bfloat16(x1 * c - x2 * sn);
  dst[j + 64] = __float2bfloat16(x2 * c + x1 * sn);
}

__global__ void rope_k(const bf16* __restrict__ qkv, const float* __restrict__ cosT,
                       const float* __restrict__ sinT, bf16* __restrict__ Kf) {
  int tid = blockIdx.x * 256 + threadIdx.x;
  int j = tid & 63, h = (tid >> 6) & 7, s = (tid >> 9) & 1023, b = tid >> 19;
  const bf16* src = qkv + ((size_t)b * SS + s) * QKVN + 2048 + h * HD;
  float x1 = __bfloat162float(src[j]), x2 = __bfloat162float(src[j + 64]);
  float c = cosT[s * 64 + j], sn = sinT[s * 64 + j];
  bf16* dst = Kf + (((size_t)(b * NKV + h)) * LT + CTXL + s) * HD;
  dst[j] = __float2bfloat16(x1 * c - x2 * sn);
  dst[j + 64] = __float2bfloat16(x2 * c + x1 * sn);
}

// ---------------- GEMM: C[M][N] = A[M][K] * BT[N][K]^T ----------------

template <typename OT>
__global__ void gemm_bt(const bf16* __restrict__ A, const bf16* __restrict__ BT,
                        OT* __restrict__ C, int M, int N, int K) {
  __shared__ __attribute__((aligned(16))) short lA[128 * 64];
  __shared__ __attribute__((aligned(16))) short lB[128 * 64];
  const int t = threadIdx.x;
  const int lane = t & 63, w = t >> 6;
  const int wm = w >> 1, wn = w & 1;
  const int lrow = lane & 15, kgrp = lane >> 4;
  const int m0 = blockIdx.y * 128, n0 = blockIdx.x * 128;
  const int rowA = w * 32 + (lane >> 3);  // +c*8 per staging call
  const int kch = (lane & 7) * 8;
  const f32x4 fz = {0.f, 0.f, 0.f, 0.f};
  f32x4 acc[4][4];
#pragma unroll
  for (int i = 0; i < 4; ++i)
#pragma unroll
    for (int j = 0; j < 4; ++j) acc[i][j] = fz;

  for (int k0 = 0; k0 < K; k0 += 64) {
    const bf16* Ag = A + (size_t)(m0 + rowA) * K + k0 + kch;
    const bf16* Bg = BT + (size_t)(n0 + rowA) * K + k0 + kch;
#pragma unroll
    for (int c = 0; c < 4; ++c) {
      gload_lds16(Ag + (size_t)(c * 8) * K, &lA[(w * 32 + c * 8) * 64]);
      gload_lds16(Bg + (size_t)(c * 8) * K, &lB[(w * 32 + c * 8) * 64]);
    }
    __syncthreads();
#pragma unroll
    for (int kk = 0; kk < 64; kk += 32) {
      s16x8 af[4], bfr[4];
#pragma unroll
      for (int i = 0; i < 4; ++i)
        af[i] = *(const s16x8*)&lA[(wm * 64 + i * 16 + lrow) * 64 + kk + kgrp * 8];
#pragma unroll
      for (int j = 0; j < 4; ++j)
        bfr[j] = *(const s16x8*)&lB[(wn * 64 + j * 16 + lrow) * 64 + kk + kgrp * 8];
#pragma unroll
      for (int i = 0; i < 4; ++i)
#pragma unroll
        for (int j = 0; j < 4; ++j) acc[i][j] = MFMA(af[i], bfr[j], acc[i][j]);
    }
    __syncthreads();
  }
#pragma unroll
  for (int i = 0; i < 4; ++i)
#pragma unroll
    for (int j = 0; j < 4; ++j)
#pragma unroll
      for (int r = 0; r < 4; ++r) {
        int row = m0 + wm * 64 + i * 16 + kgrp * 4 + r;
        int col = n0 + wn * 64 + j * 16 + lrow;
        float v = acc[i][j][r];
        if constexpr (sizeof(OT) == 2)
          C[(size_t)row * N + col] = __float2bfloat16(v);
        else
          C[(size_t)row * N + col] = v;
      }
}

// ---------------- flash attention ----------------

__global__ void flash_attn(const bf16* __restrict__ Q, const bf16* __restrict__ Kf,
                           const bf16* __restrict__ Vt, bf16* __restrict__ O) {
  __shared__ __attribute__((aligned(16))) bf16 P_lds[4][16][32];
  const int t = threadIdx.x, lane = t & 63, w = t >> 6;
  const int qb = blockIdx.x & 15, h = (blockIdx.x >> 4) & 15, b = blockIdx.x >> 8;
  const int hk = h >> 1;
  const int lrow = lane & 15, kgrp = lane >> 4;
  const bf16* Qp = Q + (((size_t)(b * NH + h)) * SS + qb * 64 + w * 16) * HD;
  s16x8 qf[4];
#pragma unroll
  for (int kd = 0; kd < 4; ++kd)
    qf[kd] = *(const s16x8*)&Qp[lrow * HD + kd * 32 + kgrp * 8];
  const f32x4 fz = {0.f, 0.f, 0.f, 0.f};
  f32x4 acc[8];
#pragma unroll
  for (int i = 0; i < 8; ++i) acc[i] = fz;
  float m_[4], l_[4];
#pragma unroll
  for (int r = 0; r < 4; ++r) { m_[r] = -1e30f; l_[r] = 0.f; }
  const bf16* Kp = Kf + (size_t)(b * NKV + hk) * LT * HD;
  const bf16* Vp = Vt + (size_t)(b * NKV + hk) * HD * LT;

  for (int l0 = 0; l0 < LT; l0 += 32) {
    f32x4 sc[2];
    sc[0] = fz;
    sc[1] = fz;
#pragma unroll
    for (int cf = 0; cf < 2; ++cf)
#pragma unroll
      for (int kd = 0; kd < 4; ++kd) {
        s16x8 kb = *(const s16x8*)&Kp[(size_t)(l0 + cf * 16 + lrow) * HD + kd * 32 + kgrp * 8];
        sc[cf] = MFMA(qf[kd], kb, sc[cf]);
      }
    const float scale = 0.08838834764831845f;
    float p0[4], p1[4], so[4];
#pragma unroll
    for (int r = 0; r < 4; ++r) {
      float s0 = sc[0][r] * scale, s1 = sc[1][r] * scale;
      float mx = fmaxf(s0, s1);
#pragma unroll
      for (int off = 1; off < 16; off <<= 1) mx = fmaxf(mx, __shfl_xor(mx, off, 16));
      float mn = fmaxf(m_[r], mx);
      so[r] = __expf(m_[r] - mn);
      p0[r] = __expf(s0 - mn);
      p1[r] = __expf(s1 - mn);
      float rs = p0[r] + p1[r];
#pragma unroll
      for (int off = 1; off < 16; off <<= 1) rs += __shfl_xor(rs, off, 16);
      l_[r] = l_[r] * so[r] + rs;
      m_[r] = mn;
    }
#pragma unroll
    for (int i = 0; i < 8; ++i)
#pragma unroll
      for (int r = 0; r < 4; ++r) acc[i][r] *= so[r];
#pragma unroll
    for (int r = 0; r < 4; ++r) {
      P_lds[w][kgrp * 4 + r][lrow] = __float2bfloat16(p0[r]);
      P_lds[w][kgrp * 4 + r][16 + lrow] = __float2bfloat16(p1[r]);
    }
    __syncthreads();
    s16x8 pa = *(const s16x8*)&P_lds[w][lrow][kgrp * 8];
#pragma unroll
    for (int nd = 0; nd < 8; ++nd) {
      s16x8 vb = *(const s16x8*)&Vp[(size_t)(nd * 16 + lrow) * LT + l0 + kgrp * 8];
      acc[nd] = MFMA(pa, vb, acc[nd]);
    }
    __syncthreads();
  }
#pragma unroll
  for (int nd = 0; nd < 8; ++nd)
#pragma unroll
    for (int r = 0; r < 4; ++r) {
      int row = qb * 64 + w * 16 + kgrp * 4 + r;
      O[((size_t)b * SS + row) * 2048 + h * HD + nd * 16 + lrow] =
          __float2bfloat16(acc[nd][r] / l_[r]);
    }
}

// ---------------- launch ----------------

extern "C" void kernel_launch(void* const* d_in, const int* in_sizes, int n_in,
                              void* d_out, int out_size, void* d_ws, size_t ws_size,
                              hipStream_t stream) {
  const float* hs = (const float*)d_in[0];
  const float* Wqkv = (const float*)d_in[1];
  const float* Wo = (const float*)d_in[2];
  const float* ctx_k = (const float*)d_in[3];
  const float* ctx_v = (const float*)d_in[4];
  const int* pid = (const int*)d_in[5];
  float* out = (float*)d_out;
  char* ws = (char*)d_ws;

  bf16* Hb = (bf16*)(ws);                      // 16.78 MB (reused as attn_out)
  bf16* WqT = (bf16*)(ws + 16777216);          // 16.78 MB
  bf16* WoT = (bf16*)(ws + 33554432);          // 8.39 MB
  bf16* qkv = (bf16*)(ws + 41943040);          // 33.55 MB
  bf16* Qb = (bf16*)(ws + 75497472);           // 16.78 MB
  bf16* Kfull = (bf16*)(ws + 92274688);        // 25.17 MB
  bf16* Vt = (bf16*)(ws + 117440512);          // 25.17 MB
  float* cosT = (float*)(ws + 142606336);      // 256 KB
  float* sinT = (float*)(ws + 142606336 + 262144);
  bf16* attn = Hb;  // alias: Hb dead after QKV GEMM

  rope_table<<<256, 256, 0, stream>>>(pid, cosT, sinT);
  cvt_bf16<<<4096, 256, 0, stream>>>(hs, Hb);
  transpose_cvt<<<dim3(128, 64), 256, 0, stream>>>(Wqkv, WqT, HID, QKVN);
  transpose_cvt<<<dim3(64, 64), 256, 0, stream>>>(Wo, WoT, 2048, 2048);
  ctxk_copy<<<4096, 256, 0, stream>>>(ctx_k, Kfull);
  ctxv_transpose<<<dim3(64, 4, 32), 256, 0, stream>>>(ctx_v, Vt);
  gemm_bt<bf16><<<dim3(QKVN / 128, MROWS / 128), 256, 0, stream>>>(
      Hb, WqT, qkv, MROWS, QKVN, HID);
  rope_q<<<16384, 256, 0, stream>>>(qkv, cosT, sinT, Qb);
  rope_k<<<8192, 256, 0, stream>>>(qkv, cosT, sinT, Kfull);
  vt_from_qkv<<<dim3(32, 4, 32), 256, 0, stream>>>(qkv, Vt);
  flash_attn<<<1024, 256, 0, stream>>>(Qb, Kfull, Vt, attn);
  gemm_bt<float><<<dim3(2048 / 128, MROWS / 128), 256, 0, stream>>>(
      attn, WoT, out, MROWS, 2048, HID);
}